// Round 1
// baseline (1257.597 us; speedup 1.0000x reference)
//
#include <hip/hip_runtime.h>
#include <float.h>

#define NLVL 12

// ---------------- adjacency build (linked lists, per-call) ----------------
__global__ void k_build_edges(const int* __restrict__ src, const int* __restrict__ dst, int E,
                              int* __restrict__ head_f, int* __restrict__ next_f,
                              int* __restrict__ head_b, int* __restrict__ next_b) {
    int e = blockIdx.x * blockDim.x + threadIdx.x;
    if (e >= E) return;
    int d = dst[e];
    next_f[e] = atomicExch(&head_f[d], e);   // in-edges of d (forward sweep)
    int s = src[e];
    next_b[e] = atomicExch(&head_b[s], e);   // out-edges of s (backward sweep)
}

// ---------------- node level histogram ----------------
__global__ void k_hist(const int* __restrict__ fl, const int* __restrict__ bl, int N,
                       int* __restrict__ counts_f, int* __restrict__ counts_b) {
    __shared__ int hf[NLVL], hb[NLVL];
    if (threadIdx.x < NLVL) { hf[threadIdx.x] = 0; hb[threadIdx.x] = 0; }
    __syncthreads();
    for (int i = blockIdx.x * blockDim.x + threadIdx.x; i < N; i += gridDim.x * blockDim.x) {
        atomicAdd(&hf[fl[i]], 1);
        atomicAdd(&hb[bl[i]], 1);
    }
    __syncthreads();
    if (threadIdx.x < NLVL) {
        atomicAdd(&counts_f[threadIdx.x], hf[threadIdx.x]);
        atomicAdd(&counts_b[threadIdx.x], hb[threadIdx.x]);
    }
}

// ---------------- tiny scan + output init ----------------
__global__ void k_scan_init(const int* __restrict__ counts_f, const int* __restrict__ counts_b,
                            int* __restrict__ base_f, int* __restrict__ base_b,
                            int* __restrict__ cursor_f, int* __restrict__ cursor_b,
                            float* __restrict__ out, int outN) {
    if (threadIdx.x == 0) {
        int s = 0;
        for (int l = 0; l < NLVL; l++) { base_f[l] = s; cursor_f[l] = s; s += counts_f[l]; }
        base_f[NLVL] = s;
        s = 0;
        for (int l = 0; l < NLVL; l++) { base_b[l] = s; cursor_b[l] = s; s += counts_b[l]; }
        base_b[NLVL] = s;
    }
    // out layout: [B][128]: cols 0..63 = max-pool (init -FLT_MAX == finfo.min), 64..127 = sum-pool (0)
    for (int i = threadIdx.x; i < outN; i += blockDim.x)
        out[i] = ((i & 127) < 64) ? -FLT_MAX : 0.0f;
}

// ---------------- scatter nodes into level buckets ----------------
__global__ void k_scatter(const int* __restrict__ fl, const int* __restrict__ bl, int N,
                          int* __restrict__ cursor_f, int* __restrict__ cursor_b,
                          int* __restrict__ nb_f, int* __restrict__ nb_b) {
    __shared__ int hf[NLVL], hb[NLVL], basef[NLVL], baseb[NLVL];
    if (threadIdx.x < NLVL) { hf[threadIdx.x] = 0; hb[threadIdx.x] = 0; }
    __syncthreads();
    int i = blockIdx.x * blockDim.x + threadIdx.x;
    bool valid = (i < N);
    int lf = 0, lb = 0;
    if (valid) {
        lf = fl[i]; lb = bl[i];
        atomicAdd(&hf[lf], 1);
        atomicAdd(&hb[lb], 1);
    }
    __syncthreads();
    if (threadIdx.x < NLVL) {
        basef[threadIdx.x] = atomicAdd(&cursor_f[threadIdx.x], hf[threadIdx.x]);
        baseb[threadIdx.x] = atomicAdd(&cursor_b[threadIdx.x], hb[threadIdx.x]);
        hf[threadIdx.x] = 0; hb[threadIdx.x] = 0;
    }
    __syncthreads();
    if (valid) {
        int pf = basef[lf] + atomicAdd(&hf[lf], 1);
        nb_f[pf] = i;
        int pb = baseb[lb] + atomicAdd(&hb[lb], 1);
        nb_b[pb] = i;
    }
}

// ---------------- encoder: h = [nt, ninv] @ W_enc + b_enc ----------------
__global__ void k_encoder(const int* __restrict__ nt, const int* __restrict__ ninv, int N,
                          const float* __restrict__ We, const float* __restrict__ be,
                          float* __restrict__ h) {
    int t = blockIdx.x * blockDim.x + threadIdx.x;   // t over N*16 float4 groups
    if (t >= N * 16) return;
    int v = t >> 4;
    int j = (t & 15) * 4;
    float a = (float)nt[v], c = (float)ninv[v];
    float4 w0 = *(const float4*)(We + j);
    float4 w1 = *(const float4*)(We + 64 + j);
    float4 b  = *(const float4*)(be + j);
    float4 r;
    r.x = fmaf(a, w0.x, fmaf(c, w1.x, b.x));
    r.y = fmaf(a, w0.y, fmaf(c, w1.y, b.y));
    r.z = fmaf(a, w0.z, fmaf(c, w1.z, b.z));
    r.w = fmaf(a, w0.w, fmaf(c, w1.w, b.w));
    *(float4*)(h + (size_t)v * 64 + j) = r;
}

// ---------------- phase 1: aggregate neighbor states for one level ----------------
// one wave per bucket node; lane = feature dim
__global__ void k_agg(const float* __restrict__ h, float* __restrict__ agg, int* __restrict__ degbuf,
                      const int* __restrict__ nb, const int* __restrict__ base, int lvl,
                      const int* __restrict__ head, const int* __restrict__ nxt,
                      const int* __restrict__ other) {
    int start = base[lvl], cnt = base[lvl + 1] - start;
    int lane  = threadIdx.x & 63;
    int wave  = (blockIdx.x * blockDim.x + threadIdx.x) >> 6;
    int nwaves = (gridDim.x * blockDim.x) >> 6;
    for (int i = wave; i < cnt; i += nwaves) {
        int v = nb[start + i];
        float acc = 0.f;
        int d = 0;
        int e = head[v];
        while (e >= 0) {
            int u = other[e];
            acc += h[(size_t)u * 64 + lane];
            d++;
            e = nxt[e];
        }
        agg[(size_t)i * 64 + lane] = acc;
        if (lane == 0) degbuf[i] = d;
    }
}

// ---------------- phase 2: h[v] = agg @ W + deg * bias ----------------
__global__ void k_matmul(float* __restrict__ h, const float* __restrict__ agg,
                         const int* __restrict__ degbuf,
                         const int* __restrict__ nb, const int* __restrict__ base, int lvl,
                         const float* __restrict__ W, const float* __restrict__ bias) {
    __shared__ float Ws[64 * 64];
    for (int i = threadIdx.x; i < 64 * 64; i += blockDim.x) Ws[i] = W[i];
    __syncthreads();
    int start = base[lvl], cnt = base[lvl + 1] - start;
    int lane  = threadIdx.x & 63;
    int wave  = (blockIdx.x * blockDim.x + threadIdx.x) >> 6;
    int nwaves = (gridDim.x * blockDim.x) >> 6;
    float bv = bias[lane];
    for (int i = wave; i < cnt; i += nwaves) {
        int v = nb[start + i];
        float a = agg[(size_t)i * 64 + lane];
        float outv = bv * (float)degbuf[i];
        #pragma unroll
        for (int k = 0; k < 64; k++) {
            outv = fmaf(__shfl(a, k, 64), Ws[k * 64 + lane], outv);
        }
        h[(size_t)v * 64 + lane] = outv;
    }
}

// ---------------- readout ----------------
__device__ inline void atomicMaxF(float* addr, float val) {
    int* ai = (int*)addr;
    int old = *ai;
    while (__int_as_float(old) < val) {
        int assumed = old;
        old = atomicCAS(ai, assumed, __float_as_int(val));
        if (old == assumed) break;
    }
}

__global__ void k_readout(const float* __restrict__ h, const int* __restrict__ nt,
                          const int* __restrict__ batch, int N, float* __restrict__ out) {
    int lane   = threadIdx.x & 63;
    int wave   = (blockIdx.x * blockDim.x + threadIdx.x) >> 6;
    int nwaves = (gridDim.x * blockDim.x) >> 6;
    int per = (N + nwaves - 1) / nwaves;
    int s = wave * per;
    if (s >= N) return;
    int e = s + per; if (e > N) e = N;
    float mx = -FLT_MAX, sm = 0.f;
    int bcur = -1;
    bool any = false;
    for (int i = s; i < e; i++) {
        int b = batch[i];
        if (b != bcur) {
            if (any) {
                atomicMaxF(&out[bcur * 128 + lane], mx);
                atomicAdd(&out[bcur * 128 + 64 + lane], sm);
            }
            bcur = b; mx = -FLT_MAX; sm = 0.f; any = false;
        }
        if (nt[i] == 1) {
            float x = h[(size_t)i * 64 + lane];
            mx = fmaxf(mx, x);
            sm += x;
            any = true;
        }
    }
    if (any) {
        atomicMaxF(&out[bcur * 128 + lane], mx);
        atomicAdd(&out[bcur * 128 + 64 + lane], sm);
    }
}

extern "C" void kernel_launch(void* const* d_in, const int* in_sizes, int n_in,
                              void* d_out, int out_size, void* d_ws, size_t ws_size,
                              hipStream_t stream) {
    const int*   node_type = (const int*)d_in[0];
    const int*   ninv      = (const int*)d_in[1];
    const int*   edge_idx  = (const int*)d_in[2];
    const int*   fl        = (const int*)d_in[3];
    const int*   bl        = (const int*)d_in[4];
    const int*   batch     = (const int*)d_in[5];
    const float* W_enc     = (const float*)d_in[6];
    const float* b_enc     = (const float*)d_in[7];
    const float* W_f       = (const float*)d_in[8];
    const float* b_f       = (const float*)d_in[9];
    const float* W_b       = (const float*)d_in[10];
    const float* b_b       = (const float*)d_in[11];

    int N = in_sizes[0];
    int E = in_sizes[2] / 2;
    const int* src = edge_idx;
    const int* dst = edge_idx + E;
    float* out = (float*)d_out;

    // ---- workspace carve-up (~110 MB) ----
    char* ws = (char*)d_ws;
    size_t off = 0;
    auto alloc = [&](size_t bytes) -> char* {
        char* p = ws + off;
        off = (off + bytes + 255) & ~(size_t)255;
        return p;
    };
    float* h      = (float*)alloc((size_t)N * 64 * sizeof(float));
    float* agg    = (float*)alloc((size_t)N * 64 * sizeof(float));
    int*   degbuf = (int*)  alloc((size_t)N * sizeof(int));
    int*   heads  = (int*)  alloc((size_t)2 * N * sizeof(int));   // head_f | head_b (one memset)
    int*   head_f = heads;
    int*   head_b = heads + N;
    int*   next_f = (int*)  alloc((size_t)E * sizeof(int));
    int*   next_b = (int*)  alloc((size_t)E * sizeof(int));
    int*   nb_f   = (int*)  alloc((size_t)N * sizeof(int));
    int*   nb_b   = (int*)  alloc((size_t)N * sizeof(int));
    int*   meta   = (int*)  alloc(6 * 16 * sizeof(int));
    int* counts_f = meta;        int* counts_b = meta + 16;
    int* cursor_f = meta + 32;   int* cursor_b = meta + 48;
    int* base_f   = meta + 64;   int* base_b   = meta + 80;

    hipMemsetAsync(heads, 0xFF, (size_t)2 * N * sizeof(int), stream);   // head = -1
    hipMemsetAsync(meta, 0, 32 * sizeof(int), stream);                  // counts = 0

    k_build_edges<<<(E + 255) / 256, 256, 0, stream>>>(src, dst, E, head_f, next_f, head_b, next_b);
    k_hist<<<256, 256, 0, stream>>>(fl, bl, N, counts_f, counts_b);
    k_scan_init<<<1, 256, 0, stream>>>(counts_f, counts_b, base_f, base_b,
                                       cursor_f, cursor_b, out, out_size);
    k_scatter<<<(N + 255) / 256, 256, 0, stream>>>(fl, bl, N, cursor_f, cursor_b, nb_f, nb_b);
    k_encoder<<<(N * 16 + 255) / 256, 256, 0, stream>>>(node_type, ninv, N, W_enc, b_enc, h);

    // forward sweep: levels 1..NLVL-1
    for (int l = 1; l < NLVL; l++) {
        k_agg<<<512, 256, 0, stream>>>(h, agg, degbuf, nb_f, base_f, l, head_f, next_f, src);
        k_matmul<<<512, 256, 0, stream>>>(h, agg, degbuf, nb_f, base_f, l, W_f, b_f);
    }
    // backward sweep
    for (int l = 1; l < NLVL; l++) {
        k_agg<<<512, 256, 0, stream>>>(h, agg, degbuf, nb_b, base_b, l, head_b, next_b, dst);
        k_matmul<<<512, 256, 0, stream>>>(h, agg, degbuf, nb_b, base_b, l, W_b, b_b);
    }

    k_readout<<<256, 256, 0, stream>>>(h, node_type, batch, N, out);
}

// Round 2
// 1030.619 us; speedup vs baseline: 1.2202x; 1.2202x over previous
//
#include <hip/hip_runtime.h>
#include <float.h>

#define NLVL 12
#define NB 16   // batches

// meta layout (ints): [0..16) counts_f | [16..32) counts_b | [32..48) counts_o
// [48..64) cursor_f | [64..80) cursor_b | [80..96) cursor_o
// [96..113) base_f | [128..145) base_b | [160..177) base_o

// ---------------- degree build: rowptr[0..N)=indeg(dst), rowptr[N..2N)=outdeg(src) ----------------
__global__ void k_build_deg(const int* __restrict__ src, const int* __restrict__ dst, int E, int N,
                            int* __restrict__ rowptr) {
    int e = blockIdx.x * blockDim.x + threadIdx.x;
    if (e >= E) return;
    atomicAdd(&rowptr[dst[e]], 1);
    atomicAdd(&rowptr[N + src[e]], 1);
}

// ---------------- 3-kernel exclusive scan over M=2N elements (in-place on rowptr) --------------
__global__ void k_scan1(int* __restrict__ data, int M, int* __restrict__ bsums) {
    __shared__ int s[512];
    int t = threadIdx.x;                    // 512 threads
    int g = blockIdx.x * 512 + t;
    int v = (g < M) ? data[g] : 0;
    s[t] = v;
    __syncthreads();
    for (int off = 1; off < 512; off <<= 1) {
        int add = (t >= off) ? s[t - off] : 0;
        __syncthreads();
        s[t] += add;
        __syncthreads();
    }
    if (g < M) data[g] = s[t] - v;          // exclusive within block
    if (t == 511) bsums[blockIdx.x] = s[511];
}

__global__ void k_scan_top(int* __restrict__ bsums, int nblk) {
    __shared__ int s[1024];
    int t = threadIdx.x;                    // 1024 threads, nblk <= 1024
    int v = (t < nblk) ? bsums[t] : 0;
    s[t] = v;
    __syncthreads();
    for (int off = 1; off < 1024; off <<= 1) {
        int add = (t >= off) ? s[t - off] : 0;
        __syncthreads();
        s[t] += add;
        __syncthreads();
    }
    if (t < nblk) bsums[t] = s[t] - v;      // exclusive block offsets
}

__global__ void k_scan_add(int* __restrict__ rowptr, int* __restrict__ cursor, int M, int total,
                           const int* __restrict__ bsums) {
    int g = blockIdx.x * blockDim.x + threadIdx.x;
    if (g >= M) return;
    int r = rowptr[g] + bsums[g >> 9];
    rowptr[g] = r;
    cursor[g] = r;
    if (g == 0) rowptr[M] = total;
}

// ---------------- CSR fill ----------------
__global__ void k_fill_csr(const int* __restrict__ src, const int* __restrict__ dst, int E, int N,
                           int* __restrict__ cursor, int* __restrict__ col) {
    int e = blockIdx.x * blockDim.x + threadIdx.x;
    if (e >= E) return;
    int s = src[e], d = dst[e];
    int p = atomicAdd(&cursor[d], 1);        // in-edges of d -> other endpoint = s
    col[p] = s;
    int q = atomicAdd(&cursor[N + s], 1);    // out-edges of s -> other endpoint = d
    col[q] = d;
}

// ---------------- histograms: levels + output-node batch counts ----------------
__global__ void k_hist(const int* __restrict__ fl, const int* __restrict__ bl,
                       const int* __restrict__ nt, const int* __restrict__ batch, int N,
                       int* __restrict__ meta) {
    __shared__ int hf[NLVL], hb[NLVL], ho[NB];
    if (threadIdx.x < NLVL) { hf[threadIdx.x] = 0; hb[threadIdx.x] = 0; }
    if (threadIdx.x < NB) ho[threadIdx.x] = 0;
    __syncthreads();
    for (int i = blockIdx.x * blockDim.x + threadIdx.x; i < N; i += gridDim.x * blockDim.x) {
        atomicAdd(&hf[fl[i]], 1);
        atomicAdd(&hb[bl[i]], 1);
        if (nt[i] == 1) atomicAdd(&ho[batch[i]], 1);
    }
    __syncthreads();
    if (threadIdx.x < NLVL) {
        atomicAdd(&meta[threadIdx.x], hf[threadIdx.x]);
        atomicAdd(&meta[16 + threadIdx.x], hb[threadIdx.x]);
    }
    if (threadIdx.x < NB) atomicAdd(&meta[32 + threadIdx.x], ho[threadIdx.x]);
}

// ---------------- tiny scans + output init ----------------
__global__ void k_scan_init(int* __restrict__ meta, float* __restrict__ out, int outN) {
    int t = threadIdx.x;
    if (t == 0) {                   // forward levels
        int s = 0;
        for (int l = 0; l < NLVL; l++) { meta[96 + l] = s; meta[48 + l] = s; s += meta[l]; }
        meta[96 + NLVL] = s;
    } else if (t == 1) {            // backward levels
        int s = 0;
        for (int l = 0; l < NLVL; l++) { meta[128 + l] = s; meta[64 + l] = s; s += meta[16 + l]; }
        meta[128 + NLVL] = s;
    } else if (t == 2) {            // output-node batches
        int s = 0;
        for (int b = 0; b < NB; b++) { meta[160 + b] = s; meta[80 + b] = s; s += meta[32 + b]; }
        meta[160 + NB] = s;
    }
    // out layout [B][128]: 0..63 max-pool (init -FLT_MAX == finfo.min), 64..127 sum-pool (0)
    for (int i = threadIdx.x; i < outN; i += blockDim.x)
        out[i] = ((i & 127) < 64) ? -FLT_MAX : 0.0f;
}

// ---------------- scatter nodes into level buckets + output-node buckets ----------------
__global__ void k_scatter(const int* __restrict__ fl, const int* __restrict__ bl,
                          const int* __restrict__ nt, const int* __restrict__ batch, int N,
                          int* __restrict__ meta,
                          int* __restrict__ nb_f, int* __restrict__ nb_b, int* __restrict__ onodes) {
    __shared__ int hf[NLVL], hb[NLVL], ho[NB], basef[NLVL], baseb[NLVL], baseo[NB];
    if (threadIdx.x < NLVL) { hf[threadIdx.x] = 0; hb[threadIdx.x] = 0; }
    if (threadIdx.x < NB) ho[threadIdx.x] = 0;
    __syncthreads();
    int i = blockIdx.x * blockDim.x + threadIdx.x;
    bool valid = (i < N);
    int lf = 0, lb = 0, ob = -1;
    if (valid) {
        lf = fl[i]; lb = bl[i];
        atomicAdd(&hf[lf], 1);
        atomicAdd(&hb[lb], 1);
        if (nt[i] == 1) { ob = batch[i]; atomicAdd(&ho[ob], 1); }
    }
    __syncthreads();
    if (threadIdx.x < NLVL) {
        basef[threadIdx.x] = atomicAdd(&meta[48 + threadIdx.x], hf[threadIdx.x]);
        baseb[threadIdx.x] = atomicAdd(&meta[64 + threadIdx.x], hb[threadIdx.x]);
        hf[threadIdx.x] = 0; hb[threadIdx.x] = 0;
    }
    if (threadIdx.x < NB) {
        baseo[threadIdx.x] = atomicAdd(&meta[80 + threadIdx.x], ho[threadIdx.x]);
        ho[threadIdx.x] = 0;
    }
    __syncthreads();
    if (valid) {
        nb_f[basef[lf] + atomicAdd(&hf[lf], 1)] = i;
        nb_b[baseb[lb] + atomicAdd(&hb[lb], 1)] = i;
        if (ob >= 0) onodes[baseo[ob] + atomicAdd(&ho[ob], 1)] = i;
    }
}

// ---------------- encoder ----------------
__global__ void k_encoder(const int* __restrict__ nt, const int* __restrict__ ninv, int N,
                          const float* __restrict__ We, const float* __restrict__ be,
                          float* __restrict__ h) {
    int t = blockIdx.x * blockDim.x + threadIdx.x;
    if (t >= N * 16) return;
    int v = t >> 4;
    int j = (t & 15) * 4;
    float a = (float)nt[v], c = (float)ninv[v];
    float4 w0 = *(const float4*)(We + j);
    float4 w1 = *(const float4*)(We + 64 + j);
    float4 b  = *(const float4*)(be + j);
    float4 r;
    r.x = fmaf(a, w0.x, fmaf(c, w1.x, b.x));
    r.y = fmaf(a, w0.y, fmaf(c, w1.y, b.y));
    r.z = fmaf(a, w0.z, fmaf(c, w1.z, b.z));
    r.w = fmaf(a, w0.w, fmaf(c, w1.w, b.w));
    *(float4*)(h + (size_t)v * 64 + j) = r;
}

// ---------------- phase 1: CSR aggregate for one level bucket ----------------
__global__ void k_agg(const float* __restrict__ h, float* __restrict__ agg,
                      const int* __restrict__ nb, const int* __restrict__ base, int lvl,
                      const int* __restrict__ rp, const int* __restrict__ col) {
    int start = base[lvl], cnt = base[lvl + 1] - start;
    int lane   = threadIdx.x & 63;
    int wave   = (blockIdx.x * blockDim.x + threadIdx.x) >> 6;
    int nwaves = (gridDim.x * blockDim.x) >> 6;
    for (int i = wave; i < cnt; i += nwaves) {
        int v = nb[start + i];
        int rpv = rp[v], rpe = rp[v + 1];
        float acc = 0.f;
        for (int cb = rpv; cb < rpe; cb += 64) {
            int ce = rpe - cb; if (ce > 64) ce = 64;
            int u = (lane < ce) ? col[cb + lane] : 0;   // one coalesced id load
            for (int j = 0; j < ce; j++) {
                int uu = __shfl(u, j, 64);
                acc += h[(size_t)uu * 64 + lane];       // independent gathers -> pipelined
            }
        }
        agg[(size_t)i * 64 + lane] = acc;
    }
}

// ---------------- phase 2: h[v] = agg @ W + deg * bias ----------------
__global__ void k_matmul(float* __restrict__ h, const float* __restrict__ agg,
                         const int* __restrict__ nb, const int* __restrict__ base, int lvl,
                         const int* __restrict__ rp,
                         const float* __restrict__ W, const float* __restrict__ bias) {
    __shared__ float Ws[64 * 64];
    for (int i = threadIdx.x; i < 64 * 64; i += blockDim.x) Ws[i] = W[i];
    __syncthreads();
    int start = base[lvl], cnt = base[lvl + 1] - start;
    int lane   = threadIdx.x & 63;
    int wave   = (blockIdx.x * blockDim.x + threadIdx.x) >> 6;
    int nwaves = (gridDim.x * blockDim.x) >> 6;
    float bv = bias[lane];
    for (int i = wave; i < cnt; i += nwaves) {
        int v = nb[start + i];
        int deg = rp[v + 1] - rp[v];
        float a = agg[(size_t)i * 64 + lane];
        float outv = bv * (float)deg;
        #pragma unroll
        for (int k = 0; k < 64; k++) {
            outv = fmaf(__shfl(a, k, 64), Ws[k * 64 + lane], outv);
        }
        h[(size_t)v * 64 + lane] = outv;
    }
}

// ---------------- readout over per-batch output-node buckets ----------------
__device__ inline void atomicMaxF(float* addr, float val) {
    int* ai = (int*)addr;
    int old = *ai;
    while (__int_as_float(old) < val) {
        int assumed = old;
        old = atomicCAS(ai, assumed, __float_as_int(val));
        if (old == assumed) break;
    }
}

__global__ void k_readout(const float* __restrict__ h, const int* __restrict__ onodes,
                          const int* __restrict__ base_o, float* __restrict__ out) {
    int b = blockIdx.x >> 5;          // batch
    int sl = blockIdx.x & 31;         // slice
    int a0 = base_o[b], a1 = base_o[b + 1];
    int cnt = a1 - a0;
    if (cnt == 0) return;
    int lo = a0 + (int)((long long)cnt * sl / 32);
    int hi = a0 + (int)((long long)cnt * (sl + 1) / 32);
    int wcnt = hi - lo;
    int wave = threadIdx.x >> 6, lane = threadIdx.x & 63;
    int wl = lo + (wcnt * wave) / 4;
    int wh = lo + (wcnt * (wave + 1)) / 4;
    if (wh <= wl) return;
    float mx = -FLT_MAX, sm = 0.f;
    for (int k = wl; k < wh; k += 64) {
        int take = wh - k; if (take > 64) take = 64;
        int idl = (lane < take) ? onodes[k + lane] : 0;  // coalesced id preload
        for (int j = 0; j < take; j++) {
            int v = __shfl(idl, j, 64);
            float x = h[(size_t)v * 64 + lane];          // dense coalesced rows
            mx = fmaxf(mx, x);
            sm += x;
        }
    }
    atomicMaxF(&out[b * 128 + lane], mx);
    atomicAdd(&out[b * 128 + 64 + lane], sm);
}

extern "C" void kernel_launch(void* const* d_in, const int* in_sizes, int n_in,
                              void* d_out, int out_size, void* d_ws, size_t ws_size,
                              hipStream_t stream) {
    const int*   node_type = (const int*)d_in[0];
    const int*   ninv      = (const int*)d_in[1];
    const int*   edge_idx  = (const int*)d_in[2];
    const int*   fl        = (const int*)d_in[3];
    const int*   bl        = (const int*)d_in[4];
    const int*   batch     = (const int*)d_in[5];
    const float* W_enc     = (const float*)d_in[6];
    const float* b_enc     = (const float*)d_in[7];
    const float* W_f       = (const float*)d_in[8];
    const float* b_f       = (const float*)d_in[9];
    const float* W_b       = (const float*)d_in[10];
    const float* b_b       = (const float*)d_in[11];

    int N = in_sizes[0];
    int E = in_sizes[2] / 2;
    int M = 2 * N;                       // concatenated in/out degree space
    const int* src = edge_idx;
    const int* dst = edge_idx + E;
    float* out = (float*)d_out;

    // ---- workspace carve-up ----
    char* ws = (char*)d_ws;
    size_t off = 0;
    auto alloc = [&](size_t bytes) -> char* {
        char* p = ws + off;
        off = (off + bytes + 255) & ~(size_t)255;
        return p;
    };
    float* h      = (float*)alloc((size_t)N * 64 * sizeof(float));
    float* agg    = (float*)alloc((size_t)N * 64 * sizeof(float));
    int*   rowptr = (int*)  alloc((size_t)(M + 1) * sizeof(int));
    int*   cursor = (int*)  alloc((size_t)M * sizeof(int));
    int*   col    = (int*)  alloc((size_t)2 * E * sizeof(int));
    int*   nb_f   = (int*)  alloc((size_t)N * sizeof(int));
    int*   nb_b   = (int*)  alloc((size_t)N * sizeof(int));
    int*   onodes = (int*)  alloc((size_t)N * sizeof(int));
    int*   bsums  = (int*)  alloc(1024 * sizeof(int));
    int*   meta   = (int*)  alloc(256 * sizeof(int));
    int* base_f = meta + 96;
    int* base_b = meta + 128;
    int* base_o = meta + 160;

    hipMemsetAsync(rowptr, 0, (size_t)(M + 1) * sizeof(int), stream);
    hipMemsetAsync(meta, 0, 48 * sizeof(int), stream);

    int nscan = (M + 511) / 512;         // 782 for N=200k (must be <= 1024)

    k_build_deg<<<(E + 255) / 256, 256, 0, stream>>>(src, dst, E, N, rowptr);
    k_scan1<<<nscan, 512, 0, stream>>>(rowptr, M, bsums);
    k_scan_top<<<1, 1024, 0, stream>>>(bsums, nscan);
    k_scan_add<<<(M + 255) / 256, 256, 0, stream>>>(rowptr, cursor, M, 2 * E, bsums);
    k_fill_csr<<<(E + 255) / 256, 256, 0, stream>>>(src, dst, E, N, cursor, col);

    k_hist<<<256, 256, 0, stream>>>(fl, bl, node_type, batch, N, meta);
    k_scan_init<<<1, 256, 0, stream>>>(meta, out, out_size);
    k_scatter<<<(N + 255) / 256, 256, 0, stream>>>(fl, bl, node_type, batch, N, meta,
                                                   nb_f, nb_b, onodes);
    k_encoder<<<(N * 16 + 255) / 256, 256, 0, stream>>>(node_type, ninv, N, W_enc, b_enc, h);

    // forward sweep: levels 1..NLVL-1 (rowptr[0..N) = in-edges, col other = src)
    for (int l = 1; l < NLVL; l++) {
        k_agg<<<1024, 256, 0, stream>>>(h, agg, nb_f, base_f, l, rowptr, col);
        k_matmul<<<512, 256, 0, stream>>>(h, agg, nb_f, base_f, l, rowptr, W_f, b_f);
    }
    // backward sweep (rowptr[N..2N) = out-edges, col other = dst)
    for (int l = 1; l < NLVL; l++) {
        k_agg<<<1024, 256, 0, stream>>>(h, agg, nb_b, base_b, l, rowptr + N, col);
        k_matmul<<<512, 256, 0, stream>>>(h, agg, nb_b, base_b, l, rowptr + N, W_b, b_b);
    }

    k_readout<<<NB * 32, 256, 0, stream>>>(h, onodes, base_o, out);
}